// Round 11
// baseline (620.565 us; speedup 1.0000x reference)
//
#include <hip/hip_runtime.h>
#include <hip/hip_fp16.h>
#include <stdint.h>
#include <math.h>

// ---------------- problem constants ----------------
namespace {
constexpr int Bn = 512, Dn = 128, Wn = 30, Kn = 5;
constexpr int HWn = 900;  // 30*30
constexpr int TQ  = 225;  // float4 pixel-quads per image

// workspace float offsets
constexpr size_t OFF_A    = 0;                        // Kn*Dn = 640
constexpr size_t OFF_SA   = OFF_A + (size_t)Kn * Dn;  // 5 (pad 8)
constexpr size_t OFF_C0   = OFF_SA + 8;               // 5 (pad 8)
constexpr size_t OFF_CNT  = 656;                      // Bn ints (zeroed per launch)
constexpr size_t OFF_PART = 1280;                     // 1024*(7*900) halves = 12.9 MB

// output float offsets (centroids, attention_maps, stop_logits concatenated)
constexpr size_t OUT_CENT = 0;
constexpr size_t OUT_ATTN = (size_t)Bn * Kn * 2;               // 5120
constexpr size_t OUT_STOP = OUT_ATTN + (size_t)Bn * Kn * HWn;  // 2309120
}  // namespace

struct FoldedKeys { uint32_t k1[5]; uint32_t k2[5]; };

// ---------------- threefry2x32 (JAX partitionable, 20 rounds) ----------------
__host__ __device__ static inline uint32_t rotl32(uint32_t x, int d) {
  return (x << d) | (x >> (32 - d));
}

__host__ __device__ static inline void threefry2x32(uint32_t k1, uint32_t k2,
                                                    uint32_t& x0, uint32_t& x1) {
  uint32_t k3 = k1 ^ k2 ^ 0x1BD11BDAu;
  x0 += k1; x1 += k2;
#define TF_R(rot) { x0 += x1; x1 = rotl32(x1, rot); x1 ^= x0; }
  TF_R(13) TF_R(15) TF_R(26) TF_R(6)   x0 += k2; x1 += k3 + 1u;
  TF_R(17) TF_R(29) TF_R(16) TF_R(24)  x0 += k3; x1 += k1 + 2u;
  TF_R(13) TF_R(15) TF_R(26) TF_R(6)   x0 += k1; x1 += k2 + 3u;
  TF_R(17) TF_R(29) TF_R(16) TF_R(24)  x0 += k2; x1 += k3 + 4u;
  TF_R(13) TF_R(15) TF_R(26) TF_R(6)   x0 += k3; x1 += k1 + 5u;
#undef TF_R
}

// ---------------- reduction helpers ----------------
__device__ static inline float wsum(float v) {
#pragma unroll
  for (int o = 32; o; o >>= 1) v += __shfl_xor(v, o, 64);
  return v;
}
__device__ static inline float bsum2(float v, float* scr) {  // 128-thread block
  v = wsum(v);
  if ((threadIdx.x & 63) == 0) scr[threadIdx.x >> 6] = v;
  __syncthreads();
  float r = scr[0] + scr[1];
  __syncthreads();
  return r;
}

// ---------------- kernel 0: per-query constants ----------------
__global__ __launch_bounds__(128) void k_prep(
    const float* __restrict__ clue, const float* __restrict__ wq,
    const float* __restrict__ bq, const float* __restrict__ wk,
    const float* __restrict__ bk, const float* __restrict__ qn_g,
    const float* __restrict__ qn_b, const float* __restrict__ fn_g,
    const float* __restrict__ fn_b, float* __restrict__ ws) {
  __shared__ float scr[2];
  __shared__ float lnc[Dn], qrow[Dn], qkrow[Dn];
  const int k = blockIdx.x, t = threadIdx.x;
  float xv = clue[(size_t)k * Dn + t];
  float m = bsum2(xv, scr) * (1.0f / Dn);
  float dd = xv - m;
  float var = bsum2(dd * dd, scr) * (1.0f / Dn);
  float r = 1.0f / sqrtf(var + 1e-5f);
  lnc[t] = dd * r * qn_g[t] + qn_b[t];
  __syncthreads();
  {
    float acc = bq[t];
    const float* wr = wq + (size_t)t * Dn;
    for (int e = 0; e < Dn; ++e) acc += lnc[e] * wr[e];
    qrow[t] = acc;
  }
  __syncthreads();
  {
    float acc = 0.f;
    for (int d = 0; d < Dn; ++d) acc += qrow[d] * wk[(size_t)d * Dn + t];
    qkrow[t] = acc;
    ws[OFF_A + (size_t)k * Dn + t] = fn_g[t] * acc;
  }
  __syncthreads();
  float sa = bsum2(fn_g[t] * qkrow[t], scr);
  float c0 = bsum2(fn_b[t] * qkrow[t] + qrow[t] * bk[t], scr);
  if (t == 0) {
    ws[OFF_SA + k] = sa;
    ws[OFF_C0 + k] = c0;
  }
}

// ---------------- kernel 1: split-A monolith with atomic ticket --------------
// grid (2, B) x 256 thr. Block (h, b): phase A on channels [h*64, h*64+64)
// with 8-deep float4 loads (R5's proven fat-load shape, 2x the blocks ->
// 16 waves/CU). Partials (sm, sq, sd[5]) per pixel stored fp16 in ws.
// Ticket: first-done block exits; second (finisher) combines partials (fixed
// h0+h1 order -> deterministic) and runs phases B/C/D for image b.
__global__ __launch_bounds__(256) void k_main(
    const float* __restrict__ x, float* __restrict__ ws,
    const float* __restrict__ wv, const float* __restrict__ bv,
    const float* __restrict__ sw1, const float* __restrict__ sb1,
    const float* __restrict__ sw2, const float* __restrict__ sb2,
    const float* __restrict__ fn_g, const float* __restrict__ fn_b,
    float* __restrict__ out, FoldedKeys keys) {
  __shared__ float Al[Kn * Dn];   // phase A: fn_g*qk ; phase D: reused as af
  __shared__ float wl[Kn * HWn];  // w = attn*rstd
  __shared__ float dots[Kn * Dn];
  __shared__ float att[Kn * Dn];
  __shared__ float hbuf[Kn * 64];
  __shared__ float scrS[4 * 5];
  __shared__ float bc[4];
  __shared__ float caL[8], entL[8];
  __shared__ int flagL;
  const int h = blockIdx.x, b = blockIdx.y, t = threadIdx.x;
  for (int i = t; i < Kn * Dn; i += 256) Al[i] = ws[OFF_A + i];
  __syncthreads();
  const bool act = (t < TQ);
  const float4* xq = (const float4*)(x + (size_t)b * Dn * HWn);

  // ---- phase A: this block's 64 channels, 8-deep float4 batches ----
  float sm[4] = {0, 0, 0, 0}, sq[4] = {0, 0, 0, 0};
  float sd[5][4] = {};
  {
    const float4* xt = xq + (size_t)(h * 64) * TQ + (act ? t : 0);
    for (int e0 = 0; e0 < 64; e0 += 8) {
      float4 vb[8];
#pragma unroll
      for (int j = 0; j < 8; ++j) vb[j] = xt[(size_t)(e0 + j) * TQ];
#pragma unroll
      for (int j = 0; j < 8; ++j) {
        const int e = h * 64 + e0 + j;
        float a0 = Al[e], a1 = Al[Dn + e], a2 = Al[2 * Dn + e],
              a3 = Al[3 * Dn + e], a4 = Al[4 * Dn + e];
        float vv[4] = {vb[j].x, vb[j].y, vb[j].z, vb[j].w};
#pragma unroll
        for (int c = 0; c < 4; ++c) {
          sm[c] += vv[c];
          sq[c] += vv[c] * vv[c];
          sd[0][c] += vv[c] * a0; sd[1][c] += vv[c] * a1;
          sd[2][c] += vv[c] * a2; sd[3][c] += vv[c] * a3;
          sd[4][c] += vv[c] * a4;
        }
      }
    }
  }
  // ---- store fp16 partials (7 arrays x 900 pixels) ----
  __half* part = (__half*)(ws + OFF_PART) + ((size_t)(2 * b + h)) * (7 * HWn);
  if (act) {
#pragma unroll
    for (int q = 0; q < 7; ++q) {
      float v0, v1, v2, v3;
      if (q == 0)      { v0 = sm[0]; v1 = sm[1]; v2 = sm[2]; v3 = sm[3]; }
      else if (q == 1) { v0 = sq[0]; v1 = sq[1]; v2 = sq[2]; v3 = sq[3]; }
      else { v0 = sd[q-2][0]; v1 = sd[q-2][1]; v2 = sd[q-2][2]; v3 = sd[q-2][3]; }
      union { __half2 h2; unsigned u; } lo, hi;
      lo.h2 = __floats2half2_rn(v0, v1);
      hi.h2 = __floats2half2_rn(v2, v3);
      *(uint2*)(part + q * HWn + 4 * t) = make_uint2(lo.u, hi.u);
    }
  }
  __threadfence();  // release: partials visible device-wide
  __syncthreads();
  if (t == 0) flagL = atomicAdd((int*)(ws + OFF_CNT) + b, 1);
  __syncthreads();
  if (flagL == 0) return;  // first-done half exits
  __threadfence();         // acquire: partner's partials now visible

  // ---- combine partials (fixed order h=0 then h=1 -> deterministic) ----
  float base[5], r[4], mr[4];
  {
    float Sm[4] = {0, 0, 0, 0}, Sq[4] = {0, 0, 0, 0}, Sd[5][4] = {};
    const __half* p0 = (const __half*)(ws + OFF_PART) + ((size_t)(2 * b)) * (7 * HWn);
    if (act) {
#pragma unroll
      for (int ph = 0; ph < 2; ++ph) {
        const __half* pp = p0 + (size_t)ph * (7 * HWn);
#pragma unroll
        for (int q = 0; q < 7; ++q) {
          uint2 v = *(const uint2*)(pp + q * HWn + 4 * t);
          union { unsigned u; __half2 h2; } lo, hi;
          lo.u = v.x; hi.u = v.y;
          float f0 = __low2float(lo.h2), f1 = __high2float(lo.h2);
          float f2 = __low2float(hi.h2), f3 = __high2float(hi.h2);
          if (q == 0) { Sm[0] += f0; Sm[1] += f1; Sm[2] += f2; Sm[3] += f3; }
          else if (q == 1) { Sq[0] += f0; Sq[1] += f1; Sq[2] += f2; Sq[3] += f3; }
          else {
            Sd[q-2][0] += f0; Sd[q-2][1] += f1; Sd[q-2][2] += f2; Sd[q-2][3] += f3;
          }
        }
      }
    }
    float SA[5], C0[5];
#pragma unroll
    for (int k = 0; k < 5; ++k) { SA[k] = ws[OFF_SA + k]; C0[k] = ws[OFF_C0 + k]; }
#pragma unroll
    for (int c = 0; c < 4; ++c) {
      float m = Sm[c] * (1.0f / Dn);
      float var = Sq[c] * (1.0f / Dn) - m * m;
      r[c] = 1.0f / sqrtf(var + 1e-5f);
      mr[c] = m * r[c];
    }
    // note: base packed per-k below to keep VGPR modest
#pragma unroll
    for (int k = 0; k < 5; ++k) base[k] = 0.f;  // placeholder; real base in bk4
    // store per-(k,c) base into a 5x4 local
    (void)base;
    // recompute into dedicated array:
    // (kept separate to preserve R5 register layout)
    float* bp = nullptr; (void)bp;
    // fallthrough handled below with bk4
#pragma unroll
    for (int k = 0; k < 5; ++k) {
      // bk4 computed on the fly in phase B loop; stash sd-combined per k,c:
      sd[k][0] = Sd[k][0]; sd[k][1] = Sd[k][1]; sd[k][2] = Sd[k][2]; sd[k][3] = Sd[k][3];
    }
    sm[0] = Sm[0]; sm[1] = Sm[1]; sm[2] = Sm[2]; sm[3] = Sm[3];
    sq[0] = Sq[0]; sq[1] = Sq[1]; sq[2] = Sq[2]; sq[3] = Sq[3];
  }
  // per-pixel base scores
  float bk4[5][4];
  {
    float SA[5], C0[5];
#pragma unroll
    for (int k = 0; k < 5; ++k) { SA[k] = ws[OFF_SA + k]; C0[k] = ws[OFF_C0 + k]; }
#pragma unroll
    for (int c = 0; c < 4; ++c) {
      float m = sm[c] * (1.0f / Dn);
#pragma unroll
      for (int k = 0; k < 5; ++k)
        bk4[k][c] = (r[c] * (sd[k][c] - m * SA[k]) + C0[k]) * 0.08838834764831844f;
    }
  }
  float cum[4] = {1.f, 1.f, 1.f, 1.f};
  float rw[4], cl[4];
#pragma unroll
  for (int c = 0; c < 4; ++c) {
    int n = 4 * t + c;
    rw[c] = (float)(n / Wn);
    cl[c] = (float)(n % Wn);
  }

  // ---- phase B: 5 gumbel-softmax steps, fixed max = 50, one reduction ----
  for (int k = 0; k < 5; ++k) {
    const uint32_t fk1 = keys.k1[k], fk2 = keys.k2[k];
    float pv[4], P[5] = {0, 0, 0, 0, 0};
#pragma unroll
    for (int c = 0; c < 4; ++c) {
      float noisy;
      if (act) {
        float s = bk4[k][c] + logf(cum[c]);
        s = fminf(fmaxf(s, -50.f), 50.f);
        uint32_t x0 = 0u, x1 = (uint32_t)(b * HWn + 4 * t + c);
        threefry2x32(fk1, fk2, x0, x1);
        uint32_t bits = x0 ^ x1;
        float u = __uint_as_float((bits >> 9) | 0x3f800000u) - 1.0f;
        u = fmaxf(u, 1e-10f);
        float g = -logf(-logf(u));
        noisy = fminf(fmaxf(s + g, -50.f), 50.f);
      } else {
        noisy = -1e30f;
      }
      float pl = noisy - 50.0f;
      float p = expf(pl);
      pv[c] = p;
      P[0] += p; P[1] += p * rw[c]; P[2] += p * cl[c];
      P[3] += p * pl; P[4] += p * mr[c];
    }
#pragma unroll
    for (int q = 0; q < 5; ++q) P[q] = wsum(P[q]);
    if ((t & 63) == 0) {
      int w = t >> 6;
#pragma unroll
      for (int q = 0; q < 5; ++q) scrS[w * 5 + q] = P[q];
    }
    __syncthreads();
    if (t == 0) {
      float S0 = 0, S1 = 0, S2 = 0, S3 = 0, S4 = 0;
#pragma unroll
      for (int w = 0; w < 4; ++w) {
        S0 += scrS[w * 5 + 0]; S1 += scrS[w * 5 + 1]; S2 += scrS[w * 5 + 2];
        S3 += scrS[w * 5 + 3]; S4 += scrS[w * 5 + 4];
      }
      const float invZ = 1.0f / S0;
      out[OUT_CENT + ((size_t)(b * Kn + k)) * 2 + 0] = S1 * invZ;
      out[OUT_CENT + ((size_t)(b * Kn + k)) * 2 + 1] = S2 * invZ;
      caL[k] = S4 * invZ;
      entL[k] = -(S3 * invZ - logf(S0)) * 0.14700905142472002f;  // 1/log(900)
      bc[0] = invZ;
    }
    __syncthreads();
    const float invZ = bc[0];
    if (act) {
      float a0 = pv[0] * invZ, a1 = pv[1] * invZ,
            a2 = pv[2] * invZ, a3 = pv[3] * invZ;
      *(float4*)&out[OUT_ATTN + ((size_t)(b * Kn + k)) * HWn + 4 * t] =
          make_float4(a0, a1, a2, a3);
      *(float4*)&wl[(size_t)k * HWn + 4 * t] =
          make_float4(a0 * r[0], a1 * r[1], a2 * r[2], a3 * r[3]);
      cum[0] = fmaxf(cum[0] * (1.0f - 0.9f * a0), 1e-6f);
      cum[1] = fmaxf(cum[1] * (1.0f - 0.9f * a1), 1e-6f);
      cum[2] = fmaxf(cum[2] * (1.0f - 0.9f * a2), 1e-6f);
      cum[3] = fmaxf(cum[3] * (1.0f - 0.9f * a3), 1e-6f);
    }
    __syncthreads();
  }

  // ---- phase C: attended dots over ALL 128 channels (L3-hot) ----
  const int lane = t & 63, wid = t >> 6;
  for (int gi = 0; gi < 4; ++gi) {
    const int g = gi * 4 + wid;
    const int d0 = g * 8;
    float acc[8][5] = {};
    for (int i0 = 0; i0 < 4; ++i0) {
      const int i = i0 * 64 + lane;
      if (i < TQ) {
        float4 v[8];
#pragma unroll
        for (int j = 0; j < 8; ++j) v[j] = xq[(size_t)(d0 + j) * TQ + i];
        float w4[5][4];
#pragma unroll
        for (int k = 0; k < 5; ++k) {
          float4 wv4 = *(const float4*)&wl[k * HWn + 4 * i];
          w4[k][0] = wv4.x; w4[k][1] = wv4.y; w4[k][2] = wv4.z; w4[k][3] = wv4.w;
        }
#pragma unroll
        for (int j = 0; j < 8; ++j)
#pragma unroll
          for (int k = 0; k < 5; ++k)
            acc[j][k] += v[j].x * w4[k][0] + v[j].y * w4[k][1] +
                         v[j].z * w4[k][2] + v[j].w * w4[k][3];
      }
    }
#pragma unroll
    for (int j = 0; j < 8; ++j)
#pragma unroll
      for (int k = 0; k < 5; ++k) {
        float s = wsum(acc[j][k]);
        if (lane == 0) dots[k * Dn + d0 + j] = s;
      }
  }
  __syncthreads();

  // ---- phase D: LN-combine + wv proj + MLP + stop ----
  float* af = Al;  // reuse
  for (int i = t; i < Kn * Dn; i += 256) {
    int k = i >> 7, e = i & 127;
    af[i] = fn_g[e] * (dots[i] - caL[k]) + fn_b[e];
  }
  __syncthreads();
  for (int i = t; i < Kn * Dn; i += 256) {
    int k = i >> 7, d2 = i & 127;
    const float4* wr = (const float4*)(wv + (size_t)d2 * Dn);
    const float4* afq = (const float4*)&af[k << 7];
    float s = bv[d2];
    for (int e = 0; e < Dn / 4; ++e) {
      float4 a = afq[e], w = wr[e];
      s += a.x * w.x + a.y * w.y + a.z * w.z + a.w * w.w;
    }
    att[i] = s;
  }
  __syncthreads();
  for (int i = t; i < Kn * 64; i += 256) {
    int k = i >> 6, j = i & 63;
    const float* sr = sw1 + (size_t)j * (Dn + 1);
    float s = sb1[j];
    for (int e = 0; e < Dn; ++e) s += sr[e] * att[(k << 7) + e];
    s += entL[k] * sr[Dn];
    // exact GELU: x * (erf(x/sqrt(2)) + 1) / 2
    hbuf[i] = s * (erff(s * 0.7071067811865475f) + 1.0f) * 0.5f;
  }
  __syncthreads();
  if (t < Kn) {
    float s = sb2[0];
    for (int j = 0; j < 64; ++j) s += hbuf[(t << 6) + j] * sw2[j];
    out[OUT_STOP + (size_t)b * Kn + t] = s;
  }
}

// ---------------- launch ----------------
extern "C" void kernel_launch(void* const* d_in, const int* in_sizes, int n_in,
                              void* d_out, int out_size, void* d_ws, size_t ws_size,
                              hipStream_t stream) {
  (void)in_sizes; (void)n_in; (void)out_size; (void)ws_size;
  const float* features = (const float*)d_in[0];
  const float* clue     = (const float*)d_in[1];
  const float* wq       = (const float*)d_in[2];
  const float* bq       = (const float*)d_in[3];
  const float* wk       = (const float*)d_in[4];
  const float* bk       = (const float*)d_in[5];
  const float* wv       = (const float*)d_in[6];
  const float* bv       = (const float*)d_in[7];
  const float* sw1      = (const float*)d_in[8];
  const float* sb1      = (const float*)d_in[9];
  const float* sw2      = (const float*)d_in[10];
  const float* sb2      = (const float*)d_in[11];
  const float* qn_g     = (const float*)d_in[12];
  const float* qn_b     = (const float*)d_in[13];
  const float* fn_g     = (const float*)d_in[14];
  const float* fn_b     = (const float*)d_in[15];
  float* ws  = (float*)d_ws;
  float* out = (float*)d_out;

  // fold_in(key(42), k) on host: full threefry of (0,k) with key (0,42).
  FoldedKeys fk;
  for (int k = 0; k < Kn; ++k) {
    uint32_t x0 = 0u, x1 = (uint32_t)k;
    threefry2x32(0u, 42u, x0, x1);
    fk.k1[k] = x0; fk.k2[k] = x1;
  }

  // reset the per-image ticket counters (graph-capture-safe stream op)
  hipMemsetAsync((char*)d_ws + OFF_CNT * sizeof(float), 0, Bn * sizeof(int),
                 stream);
  hipLaunchKernelGGL(k_prep, dim3(Kn), dim3(128), 0, stream,
                     clue, wq, bq, wk, bk, qn_g, qn_b, fn_g, fn_b, ws);
  hipLaunchKernelGGL(k_main, dim3(2, Bn), dim3(256), 0, stream,
                     features, ws, wv, bv, sw1, sb1, sw2, sb2, fn_g, fn_b,
                     out, fk);
}

// Round 12
// 183.696 us; speedup vs baseline: 3.3782x; 3.3782x over previous
//
#include <hip/hip_runtime.h>
#include <stdint.h>
#include <math.h>

// ---------------- problem constants ----------------
namespace {
constexpr int Bn = 512, Dn = 128, Wn = 30, Kn = 5;
constexpr int HWn = 900;   // 30*30
constexpr int TQ  = 225;   // float4 pixel-quads per image

// workspace float offsets (tiny: only per-query constants)
constexpr size_t OFF_A  = 0;                         // Kn*Dn = 640
constexpr size_t OFF_SA = OFF_A + (size_t)Kn * Dn;   // 5 (pad 8)
constexpr size_t OFF_C0 = OFF_SA + 8;                // 5 (pad 8)

// output float offsets (centroids, attention_maps, stop_logits concatenated)
constexpr size_t OUT_CENT = 0;
constexpr size_t OUT_ATTN = (size_t)Bn * Kn * 2;               // 5120
constexpr size_t OUT_STOP = OUT_ATTN + (size_t)Bn * Kn * HWn;  // 2309120
}  // namespace

struct FoldedKeys { uint32_t k1[5]; uint32_t k2[5]; };

// ---------------- threefry2x32 (JAX partitionable, 20 rounds) ----------------
__host__ __device__ static inline uint32_t rotl32(uint32_t x, int d) {
  return (x << d) | (x >> (32 - d));
}

__host__ __device__ static inline void threefry2x32(uint32_t k1, uint32_t k2,
                                                    uint32_t& x0, uint32_t& x1) {
  uint32_t k3 = k1 ^ k2 ^ 0x1BD11BDAu;
  x0 += k1; x1 += k2;
#define TF_R(rot) { x0 += x1; x1 = rotl32(x1, rot); x1 ^= x0; }
  TF_R(13) TF_R(15) TF_R(26) TF_R(6)   x0 += k2; x1 += k3 + 1u;
  TF_R(17) TF_R(29) TF_R(16) TF_R(24)  x0 += k3; x1 += k1 + 2u;
  TF_R(13) TF_R(15) TF_R(26) TF_R(6)   x0 += k1; x1 += k2 + 3u;
  TF_R(17) TF_R(29) TF_R(16) TF_R(24)  x0 += k2; x1 += k3 + 4u;
  TF_R(13) TF_R(15) TF_R(26) TF_R(6)   x0 += k3; x1 += k1 + 5u;
#undef TF_R
}

// ---------------- reduction helpers ----------------
__device__ static inline float wsum(float v) {
#pragma unroll
  for (int o = 32; o; o >>= 1) v += __shfl_xor(v, o, 64);
  return v;
}
__device__ static inline float bsum2(float v, float* scr) {  // 128-thread block
  v = wsum(v);
  if ((threadIdx.x & 63) == 0) scr[threadIdx.x >> 6] = v;
  __syncthreads();
  float r = scr[0] + scr[1];
  __syncthreads();
  return r;
}

// ---------------- kernel 0: per-query constants ----------------
// q = LN(clue)@wq.T+bq ; qk = q@wk ; A = fn_g*qk ; SA = sum A ; C0 = fn_b.qk + q.bk
__global__ __launch_bounds__(128) void k_prep(
    const float* __restrict__ clue, const float* __restrict__ wq,
    const float* __restrict__ bq, const float* __restrict__ wk,
    const float* __restrict__ bk, const float* __restrict__ qn_g,
    const float* __restrict__ qn_b, const float* __restrict__ fn_g,
    const float* __restrict__ fn_b, float* __restrict__ ws) {
  __shared__ float scr[2];
  __shared__ float lnc[Dn], qrow[Dn], qkrow[Dn];
  const int k = blockIdx.x, t = threadIdx.x;
  float xv = clue[(size_t)k * Dn + t];
  float m = bsum2(xv, scr) * (1.0f / Dn);
  float dd = xv - m;
  float var = bsum2(dd * dd, scr) * (1.0f / Dn);
  float r = 1.0f / sqrtf(var + 1e-5f);
  lnc[t] = dd * r * qn_g[t] + qn_b[t];
  __syncthreads();
  {
    float acc = bq[t];
    const float* wr = wq + (size_t)t * Dn;
    for (int e = 0; e < Dn; ++e) acc += lnc[e] * wr[e];
    qrow[t] = acc;
  }
  __syncthreads();
  {
    float acc = 0.f;
    for (int d = 0; d < Dn; ++d) acc += qrow[d] * wk[(size_t)d * Dn + t];
    qkrow[t] = acc;
    ws[OFF_A + (size_t)k * Dn + t] = fn_g[t] * acc;
  }
  __syncthreads();
  float sa = bsum2(fn_g[t] * qkrow[t], scr);
  float c0 = bsum2(fn_b[t] * qkrow[t] + qrow[t] * bk[t], scr);
  if (t == 0) {
    ws[OFF_SA + k] = sa;
    ws[OFF_C0 + k] = c0;
  }
}

// ---------------- kernel 1: everything per image, fully fused ----------------
// R5 structure (best measured: 124.9 us) + two validated deltas:
//  * phase A software pipeline: prefetch-4 / consume-4 float4 double-buffer
//  * phase B fixed-max softmax (noisy<=50 -> p=exp(noisy-50), ratios exact):
//    ONE 5-value reduction round per k instead of max+Z+4-sum rounds.
// Phase C: re-read image in reverse channel order (L3-hot). Phase D: MLP.
__global__ __launch_bounds__(256) void k_all(
    const float* __restrict__ x, const float* __restrict__ ws,
    const float* __restrict__ wv, const float* __restrict__ bv,
    const float* __restrict__ sw1, const float* __restrict__ sb1,
    const float* __restrict__ sw2, const float* __restrict__ sb2,
    const float* __restrict__ fn_g, const float* __restrict__ fn_b,
    float* __restrict__ out, FoldedKeys keys) {
  __shared__ float Al[Kn * Dn];   // phase A: fn_g*qk ; phase D: reused as af
  __shared__ float wl[Kn * HWn];  // w = attn*rstd
  __shared__ float dots[Kn * Dn];
  __shared__ float att[Kn * Dn];
  __shared__ float hbuf[Kn * 64];
  __shared__ float scrS[4 * 5];   // per-warp partials, 5 sums
  __shared__ float bc[4];         // broadcast 1/Z
  __shared__ float caL[8], entL[8];
  const int b = blockIdx.x, t = threadIdx.x;
  for (int i = t; i < Kn * Dn; i += 256) Al[i] = ws[OFF_A + i];
  __syncthreads();
  const bool act = (t < TQ);
  const float4* xq = (const float4*)(x + (size_t)b * Dn * HWn);

  // ---- phase A: stream this image once; prefetch-4/consume-4 pipeline ----
  float sm[4] = {0, 0, 0, 0}, sq[4] = {0, 0, 0, 0};
  float sd[5][4] = {};
  {
    const float4* xt = xq + (act ? t : 0);
    float4 cur[4], nxt[4];
#pragma unroll
    for (int j = 0; j < 4; ++j) cur[j] = xt[(size_t)j * TQ];
    for (int e0 = 0; e0 < Dn; e0 += 4) {
      if (e0 + 4 < Dn) {
#pragma unroll
        for (int j = 0; j < 4; ++j) nxt[j] = xt[(size_t)(e0 + 4 + j) * TQ];
      }
#pragma unroll
      for (int j = 0; j < 4; ++j) {
        const int e = e0 + j;
        float a0 = Al[e], a1 = Al[Dn + e], a2 = Al[2 * Dn + e],
              a3 = Al[3 * Dn + e], a4 = Al[4 * Dn + e];
        float vv[4] = {cur[j].x, cur[j].y, cur[j].z, cur[j].w};
#pragma unroll
        for (int c = 0; c < 4; ++c) {
          sm[c] += vv[c];
          sq[c] += vv[c] * vv[c];
          sd[0][c] += vv[c] * a0; sd[1][c] += vv[c] * a1;
          sd[2][c] += vv[c] * a2; sd[3][c] += vv[c] * a3;
          sd[4][c] += vv[c] * a4;
        }
      }
#pragma unroll
      for (int j = 0; j < 4; ++j) cur[j] = nxt[j];
    }
  }
  float r[4], mr[4], base[5][4], cum[4], rw[4], cl[4];
  {
    float SA[5], C0[5];
#pragma unroll
    for (int k = 0; k < 5; ++k) { SA[k] = ws[OFF_SA + k]; C0[k] = ws[OFF_C0 + k]; }
#pragma unroll
    for (int c = 0; c < 4; ++c) {
      float m = sm[c] * (1.0f / Dn);
      float var = sq[c] * (1.0f / Dn) - m * m;
      r[c] = 1.0f / sqrtf(var + 1e-5f);
      mr[c] = m * r[c];
      cum[c] = 1.0f;
      int n = 4 * t + c;
      rw[c] = (float)(n / Wn);
      cl[c] = (float)(n % Wn);
#pragma unroll
      for (int k = 0; k < 5; ++k)
        base[k][c] = (r[c] * (sd[k][c] - m * SA[k]) + C0[k]) *
                     0.08838834764831844f;  // 1/sqrt(128)
    }
  }

  // ---- phase B: 5 gumbel-softmax steps, fixed max = 50, one reduction ----
  for (int k = 0; k < 5; ++k) {
    const uint32_t fk1 = keys.k1[k], fk2 = keys.k2[k];
    float pv[4], P[5] = {0, 0, 0, 0, 0};
#pragma unroll
    for (int c = 0; c < 4; ++c) {
      float noisy;
      if (act) {
        float s = base[k][c] + logf(cum[c]);
        s = fminf(fmaxf(s, -50.f), 50.f);
        uint32_t x0 = 0u, x1 = (uint32_t)(b * HWn + 4 * t + c);  // counter (0,j)
        threefry2x32(fk1, fk2, x0, x1);
        uint32_t bits = x0 ^ x1;
        float u = __uint_as_float((bits >> 9) | 0x3f800000u) - 1.0f;
        u = fmaxf(u, 1e-10f);
        float g = -logf(-logf(u));
        noisy = fminf(fmaxf(s + g, -50.f), 50.f);
      } else {
        noisy = -1e30f;
      }
      float pl = noisy - 50.0f;  // log of unnormalized p
      float p = expf(pl);        // exactly 0 for inactive lanes
      pv[c] = p;
      P[0] += p; P[1] += p * rw[c]; P[2] += p * cl[c];
      P[3] += p * pl; P[4] += p * mr[c];
    }
#pragma unroll
    for (int q = 0; q < 5; ++q) P[q] = wsum(P[q]);
    if ((t & 63) == 0) {
      int w = t >> 6;
#pragma unroll
      for (int q = 0; q < 5; ++q) scrS[w * 5 + q] = P[q];
    }
    __syncthreads();
    if (t == 0) {
      float S0 = 0, S1 = 0, S2 = 0, S3 = 0, S4 = 0;
#pragma unroll
      for (int w = 0; w < 4; ++w) {
        S0 += scrS[w * 5 + 0]; S1 += scrS[w * 5 + 1]; S2 += scrS[w * 5 + 2];
        S3 += scrS[w * 5 + 3]; S4 += scrS[w * 5 + 4];
      }
      const float invZ = 1.0f / S0;
      out[OUT_CENT + ((size_t)(b * Kn + k)) * 2 + 0] = S1 * invZ;
      out[OUT_CENT + ((size_t)(b * Kn + k)) * 2 + 1] = S2 * invZ;
      caL[k] = S4 * invZ;
      // sum a*log a = S3/Z - log Z ; ent = -(that)/log(900)
      entL[k] = -(S3 * invZ - logf(S0)) * 0.14700905142472002f;  // 1/log(900)
      bc[0] = invZ;
    }
    __syncthreads();
    const float invZ = bc[0];
    if (act) {
      float a0 = pv[0] * invZ, a1 = pv[1] * invZ,
            a2 = pv[2] * invZ, a3 = pv[3] * invZ;
      *(float4*)&out[OUT_ATTN + ((size_t)(b * Kn + k)) * HWn + 4 * t] =
          make_float4(a0, a1, a2, a3);
      *(float4*)&wl[(size_t)k * HWn + 4 * t] =
          make_float4(a0 * r[0], a1 * r[1], a2 * r[2], a3 * r[3]);
      cum[0] = fmaxf(cum[0] * (1.0f - 0.9f * a0), 1e-6f);
      cum[1] = fmaxf(cum[1] * (1.0f - 0.9f * a1), 1e-6f);
      cum[2] = fmaxf(cum[2] * (1.0f - 0.9f * a2), 1e-6f);
      cum[3] = fmaxf(cum[3] * (1.0f - 0.9f * a3), 1e-6f);
    }
    __syncthreads();  // protect scrS/bc before next k
  }

  // ---- phase C: attended dots; re-read image in reverse channel order ----
  const int lane = t & 63, wid = t >> 6;
  for (int gi = 0; gi < 4; ++gi) {
    const int g = 15 - (gi * 4 + wid);  // descending channel groups
    const int d0 = g * 8;
    float acc[8][5] = {};
    for (int i0 = 0; i0 < 4; ++i0) {
      const int i = i0 * 64 + lane;
      if (i < TQ) {
        float4 v[8];
#pragma unroll
        for (int j = 0; j < 8; ++j) v[j] = xq[(size_t)(d0 + j) * TQ + i];
        float w4[5][4];
#pragma unroll
        for (int k = 0; k < 5; ++k) {
          float4 wv4 = *(const float4*)&wl[k * HWn + 4 * i];
          w4[k][0] = wv4.x; w4[k][1] = wv4.y; w4[k][2] = wv4.z; w4[k][3] = wv4.w;
        }
#pragma unroll
        for (int j = 0; j < 8; ++j)
#pragma unroll
          for (int k = 0; k < 5; ++k)
            acc[j][k] += v[j].x * w4[k][0] + v[j].y * w4[k][1] +
                         v[j].z * w4[k][2] + v[j].w * w4[k][3];
      }
    }
#pragma unroll
    for (int j = 0; j < 8; ++j)
#pragma unroll
      for (int k = 0; k < 5; ++k) {
        float s = wsum(acc[j][k]);
        if (lane == 0) dots[k * Dn + d0 + j] = s;
      }
  }
  __syncthreads();

  // ---- phase D: LN-combine + wv proj + MLP + stop ----
  float* af = Al;  // reuse (phase-A use of Al is long done)
  for (int i = t; i < Kn * Dn; i += 256) {
    int k = i >> 7, e = i & 127;
    af[i] = fn_g[e] * (dots[i] - caL[k]) + fn_b[e];
  }
  __syncthreads();
  for (int i = t; i < Kn * Dn; i += 256) {
    int k = i >> 7, d2 = i & 127;
    const float4* wr = (const float4*)(wv + (size_t)d2 * Dn);
    const float4* afq = (const float4*)&af[k << 7];
    float s = bv[d2];
    for (int e = 0; e < Dn / 4; ++e) {
      float4 a = afq[e], w = wr[e];
      s += a.x * w.x + a.y * w.y + a.z * w.z + a.w * w.w;
    }
    att[i] = s;
  }
  __syncthreads();
  for (int i = t; i < Kn * 64; i += 256) {
    int k = i >> 6, j = i & 63;
    const float* sr = sw1 + (size_t)j * (Dn + 1);
    float s = sb1[j];
    for (int e = 0; e < Dn; ++e) s += sr[e] * att[(k << 7) + e];
    s += entL[k] * sr[Dn];
    // exact GELU: x * (erf(x/sqrt(2)) + 1) / 2
    hbuf[i] = s * (erff(s * 0.7071067811865475f) + 1.0f) * 0.5f;
  }
  __syncthreads();
  if (t < Kn) {
    float s = sb2[0];
    for (int j = 0; j < 64; ++j) s += hbuf[(t << 6) + j] * sw2[j];
    out[OUT_STOP + (size_t)b * Kn + t] = s;
  }
}

// ---------------- launch ----------------
extern "C" void kernel_launch(void* const* d_in, const int* in_sizes, int n_in,
                              void* d_out, int out_size, void* d_ws, size_t ws_size,
                              hipStream_t stream) {
  (void)in_sizes; (void)n_in; (void)out_size; (void)ws_size;
  const float* features = (const float*)d_in[0];
  const float* clue     = (const float*)d_in[1];
  const float* wq       = (const float*)d_in[2];
  const float* bq       = (const float*)d_in[3];
  const float* wk       = (const float*)d_in[4];
  const float* bk       = (const float*)d_in[5];
  const float* wv       = (const float*)d_in[6];
  const float* bv       = (const float*)d_in[7];
  const float* sw1      = (const float*)d_in[8];
  const float* sb1      = (const float*)d_in[9];
  const float* sw2      = (const float*)d_in[10];
  const float* sb2      = (const float*)d_in[11];
  const float* qn_g     = (const float*)d_in[12];
  const float* qn_b     = (const float*)d_in[13];
  const float* fn_g     = (const float*)d_in[14];
  const float* fn_b     = (const float*)d_in[15];
  float* ws  = (float*)d_ws;
  float* out = (float*)d_out;

  // fold_in(key(42), k) on host: full threefry of (0,k) with key (0,42).
  FoldedKeys fk;
  for (int k = 0; k < Kn; ++k) {
    uint32_t x0 = 0u, x1 = (uint32_t)k;
    threefry2x32(0u, 42u, x0, x1);
    fk.k1[k] = x0; fk.k2[k] = x1;
  }

  hipLaunchKernelGGL(k_prep, dim3(Kn), dim3(128), 0, stream,
                     clue, wq, bq, wk, bk, qn_g, qn_b, fn_g, fn_b, ws);
  hipLaunchKernelGGL(k_all, dim3(Bn), dim3(256), 0, stream,
                     features, ws, wv, bv, sw1, sb1, sw2, sb2, fn_g, fn_b,
                     out, fk);
}